// Round 1
// baseline (20.709 us; speedup 1.0000x reference)
//
#include <hip/hip_runtime.h>
#include <hip/hip_bf16.h>

#define NB 64
#define LQ 32
#define LD 256
#define DD 128
#define NWAY 8
#define KT 32
#define LDSROW 136   // 128 + 8 bf16 pad -> 272B row stride, 16B aligned

typedef __attribute__((ext_vector_type(8))) short short8;
typedef __attribute__((ext_vector_type(4))) float f32x4;

static __device__ __forceinline__ unsigned short f2bf(float f) {
    unsigned int u = __float_as_uint(f);
    u += 0x7fffu + ((u >> 16) & 1u);   // round-to-nearest-even
    return (unsigned short)(u >> 16);
}

// One block per (b, n). 256 threads = 4 waves: wave = (khalf<<1)|qhalf.
__global__ __launch_bounds__(256) void colbert_scores_kernel(
    const float* __restrict__ qreps,   // [B][LQ][DD]
    const float* __restrict__ dreps,   // [B][NWAY][LD][DD]
    const int*   __restrict__ masks,   // [B][NWAY][LD]
    float*       __restrict__ scores)  // [B*NWAY]
{
    const int bn  = blockIdx.x;        // 0..511
    const int b   = bn >> 3;
    const int tid = threadIdx.x;
    const int lane = tid & 63;
    const int w    = tid >> 6;         // wave id 0..3
    const int qh   = w & 1;            // q half (0/1)
    const int kh   = w >> 1;           // k half (0/1)

    __shared__ unsigned short qs[LQ * LDSROW];   // normalized queries, bf16
    __shared__ unsigned short ds_[KT * LDSROW];  // normalized doc tile, bf16
    __shared__ int   mks[LD];
    __shared__ float qmax[2][LQ];

    // ---- load masks for this (b,n) ----
    for (int i = tid; i < LD; i += 256) mks[i] = masks[(size_t)bn * LD + i];

    // ---- normalize queries into LDS (32 rows x 8 threads/row, 16 elems each) ----
    {
        const int row = tid >> 3, seg = tid & 7;
        const float* src = qreps + ((size_t)b * LQ + row) * DD + seg * 16;
        float v[16];
        float ss = 0.f;
        #pragma unroll
        for (int i = 0; i < 16; i += 4) {
            float4 f = *reinterpret_cast<const float4*>(src + i);
            v[i] = f.x; v[i+1] = f.y; v[i+2] = f.z; v[i+3] = f.w;
            ss += f.x*f.x + f.y*f.y + f.z*f.z + f.w*f.w;
        }
        ss += __shfl_xor(ss, 1); ss += __shfl_xor(ss, 2); ss += __shfl_xor(ss, 4);
        const float rn = rsqrtf(fmaxf(ss, 1e-24f));
        unsigned short tmp[16];
        #pragma unroll
        for (int i = 0; i < 16; ++i) tmp[i] = f2bf(v[i] * rn);
        unsigned short* dst = &qs[row * LDSROW + seg * 16];
        *reinterpret_cast<uint4*>(dst)     = *reinterpret_cast<const uint4*>(&tmp[0]);
        *reinterpret_cast<uint4*>(dst + 8) = *reinterpret_cast<const uint4*>(&tmp[8]);
    }
    __syncthreads();

    // ---- MFMA fragment base addresses ----
    const int frow  = lane & 15;       // fragment row (16 lanes)
    const int fpack = lane >> 4;       // k-chunk group 0..3
    const unsigned short* aptr = &qs[(qh * 16 + frow) * LDSROW + fpack * 8];

    float rmax[4] = {-1e30f, -1e30f, -1e30f, -1e30f};

    for (int t = 0; t < LD / KT; ++t) {
        // ---- stage + normalize doc tile (32 rows) ----
        {
            const int row = tid >> 3, seg = tid & 7;
            const float* src = dreps + ((size_t)bn * LD + t * KT + row) * DD + seg * 16;
            float v[16];
            float ss = 0.f;
            #pragma unroll
            for (int i = 0; i < 16; i += 4) {
                float4 f = *reinterpret_cast<const float4*>(src + i);
                v[i] = f.x; v[i+1] = f.y; v[i+2] = f.z; v[i+3] = f.w;
                ss += f.x*f.x + f.y*f.y + f.z*f.z + f.w*f.w;
            }
            ss += __shfl_xor(ss, 1); ss += __shfl_xor(ss, 2); ss += __shfl_xor(ss, 4);
            const float rn = rsqrtf(fmaxf(ss, 1e-24f));
            unsigned short tmp[16];
            #pragma unroll
            for (int i = 0; i < 16; ++i) tmp[i] = f2bf(v[i] * rn);
            unsigned short* dst = &ds_[row * LDSROW + seg * 16];
            *reinterpret_cast<uint4*>(dst)     = *reinterpret_cast<const uint4*>(&tmp[0]);
            *reinterpret_cast<uint4*>(dst + 8) = *reinterpret_cast<const uint4*>(&tmp[8]);
        }
        __syncthreads();

        // ---- 16x16 output tile per wave: D[q][k] over K=128 (4 MFMAs) ----
        f32x4 acc = {0.f, 0.f, 0.f, 0.f};
        const unsigned short* bptr = &ds_[(kh * 16 + frow) * LDSROW + fpack * 8];
        #pragma unroll
        for (int kc = 0; kc < 4; ++kc) {
            short8 a  = *reinterpret_cast<const short8*>(aptr + kc * 32);
            short8 bb = *reinterpret_cast<const short8*>(bptr + kc * 32);
            acc = __builtin_amdgcn_mfma_f32_16x16x32_bf16(a, bb, acc, 0, 0, 0);
        }

        // ---- masked running max over k columns ----
        const int col = t * KT + kh * 16 + (lane & 15);
        if (mks[col]) {
            #pragma unroll
            for (int r = 0; r < 4; ++r) rmax[r] = fmaxf(rmax[r], acc[r]);
        }
        __syncthreads();   // protect ds_ before next staging
    }

    // ---- reduce max across the 16 k-columns within the wave ----
    #pragma unroll
    for (int r = 0; r < 4; ++r) {
        float m = rmax[r];
        m = fmaxf(m, __shfl_xor(m, 1));
        m = fmaxf(m, __shfl_xor(m, 2));
        m = fmaxf(m, __shfl_xor(m, 4));
        m = fmaxf(m, __shfl_xor(m, 8));
        rmax[r] = m;
    }
    if ((lane & 15) == 0) {
        const int qrow = qh * 16 + (lane >> 4) * 4;
        #pragma unroll
        for (int r = 0; r < 4; ++r) qmax[kh][qrow + r] = rmax[r];
    }
    __syncthreads();

    // ---- combine k-halves, sum over 32 q rows ----
    if (w == 0) {
        float s = (lane < 32) ? fmaxf(qmax[0][lane], qmax[1][lane]) : 0.f;
        s += __shfl_xor(s, 1);  s += __shfl_xor(s, 2);  s += __shfl_xor(s, 4);
        s += __shfl_xor(s, 8);  s += __shfl_xor(s, 16); s += __shfl_xor(s, 32);
        if (lane == 0) scores[bn] = s;
    }
}

// One wave: thread b handles batch row b.
__global__ __launch_bounds__(64) void colbert_loss_kernel(
    const float* __restrict__ scores,   // [B*NWAY]
    const float* __restrict__ labels,   // [B][2*NWAY]
    float*       __restrict__ out)
{
    const int b = threadIdx.x;
    float sc[NWAY];
    float m = -1e30f;
    #pragma unroll
    for (int j = 0; j < NWAY; ++j) { sc[j] = scores[b * NWAY + j]; m = fmaxf(m, sc[j]); }
    float se = 0.f;
    #pragma unroll
    for (int j = 0; j < NWAY; ++j) se += expf(sc[j] - m);
    const float lse = m + logf(se);

    float lossb = 0.f, posb = 0.f;
    #pragma unroll
    for (int j = 0; j < NWAY; ++j) {
        const float ls = sc[j] - lse;
        const float tg = labels[b * 2 * NWAY + j];
        const float wv = labels[b * 2 * NWAY + NWAY + j];
        lossb += expf(tg) * (tg - ls);
        posb  += ls * wv;
    }
    float a = lossb, p = posb;
    #pragma unroll
    for (int d = 1; d < 64; d <<= 1) { a += __shfl_xor(a, d); p += __shfl_xor(p, d); }
    if (b == 0) out[0] = a / 512.0f - 0.1f * p;
}

extern "C" void kernel_launch(void* const* d_in, const int* in_sizes, int n_in,
                              void* d_out, int out_size, void* d_ws, size_t ws_size,
                              hipStream_t stream) {
    const float* qreps  = (const float*)d_in[0];
    const float* dreps  = (const float*)d_in[1];
    const int*   masks  = (const int*)d_in[2];
    const float* labels = (const float*)d_in[3];
    float* scores = (float*)d_ws;            // 512 floats
    float* out    = (float*)d_out;

    colbert_scores_kernel<<<NB * NWAY, 256, 0, stream>>>(qreps, dreps, masks, scores);
    colbert_loss_kernel<<<1, 64, 0, stream>>>(scores, labels, out);
}

// Round 2
// 18.846 us; speedup vs baseline: 1.0989x; 1.0989x over previous
//
#include <hip/hip_runtime.h>
#include <hip/hip_bf16.h>

#define NB 64
#define LQ 32
#define LD 256
#define DD 128
#define NWAY 8
#define KT 64            // doc rows per tile
#define NT (LD / KT)     // 4 tiles
#define LDSROW 136       // 128 + 8 bf16 pad -> 272B row stride (<=2-way bank alias, free)

typedef __attribute__((ext_vector_type(8))) short short8;
typedef __attribute__((ext_vector_type(4))) float f32x4;

static __device__ __forceinline__ unsigned short f2bf(float f) {
    unsigned int u = __float_as_uint(f);
    u += 0x7fffu + ((u >> 16) & 1u);   // round-to-nearest-even
    return (unsigned short)(u >> 16);
}

// One block per (b, n). 512 threads = 8 waves: wave = (kq<<1)|qh.
// kq in 0..3 selects 16 of the 64 k-columns of the tile; qh selects 16 of 32 q rows.
__global__ __launch_bounds__(512, 4) void colbert_scores_kernel(
    const float* __restrict__ qreps,   // [B][LQ][DD]
    const float* __restrict__ dreps,   // [B][NWAY][LD][DD]
    const int*   __restrict__ masks,   // [B][NWAY][LD]
    float*       __restrict__ scores)  // [B*NWAY]
{
    const int bn   = blockIdx.x;       // 0..511
    const int b    = bn >> 3;
    const int tid  = threadIdx.x;
    const int lane = tid & 63;
    const int w    = tid >> 6;         // wave id 0..7
    const int qh   = w & 1;            // q half (0/1)
    const int kq   = w >> 1;           // k quarter (0..3)

    __shared__ __align__(16) unsigned short qs[LQ * LDSROW];   // normalized queries, bf16
    __shared__ __align__(16) unsigned short ds_[KT * LDSROW];  // normalized doc tile, bf16
    __shared__ int   mks[LD];
    __shared__ float qmax[4][LQ];

    // ---- masks for this (b,n); zero-init ds_ so first-tile masked rows are finite ----
    if (tid < LD) mks[tid] = masks[(size_t)bn * LD + tid];
    {
        uint4 z = {0u, 0u, 0u, 0u};
        for (int i = tid; i < KT * LDSROW / 8; i += 512)
            reinterpret_cast<uint4*>(ds_)[i] = z;
    }
    __syncthreads();

    const int row = tid >> 3;          // 0..63 (doc row within tile)
    const int seg = tid & 7;           // 16-float segment within the row

    float va[16], vb[16];

    // prefetch: issue global loads for tile t into regs (masked rows skipped)
    auto prefetch = [&](float (&v)[16], int t) {
        if (mks[t * KT + row]) {
            const float* src = dreps + ((size_t)bn * LD + t * KT + row) * DD + seg * 16;
            #pragma unroll
            for (int i = 0; i < 4; ++i) {
                float4 f = *reinterpret_cast<const float4*>(src + i * 4);
                v[i*4+0] = f.x; v[i*4+1] = f.y; v[i*4+2] = f.z; v[i*4+3] = f.w;
            }
        }
    };

    // normalize regs -> bf16 LDS (masked rows: leave stale finite data; never read)
    auto stagewrite = [&](float (&v)[16], int t) {
        if (mks[t * KT + row]) {
            float ss = 0.f;
            #pragma unroll
            for (int i = 0; i < 16; ++i) ss += v[i] * v[i];
            ss += __shfl_xor(ss, 1); ss += __shfl_xor(ss, 2); ss += __shfl_xor(ss, 4);
            const float rn = rsqrtf(fmaxf(ss, 1e-24f));
            unsigned short tmp[16];
            #pragma unroll
            for (int i = 0; i < 16; ++i) tmp[i] = f2bf(v[i] * rn);
            unsigned short* dst = &ds_[row * LDSROW + seg * 16];
            *reinterpret_cast<uint4*>(dst)     = *reinterpret_cast<const uint4*>(&tmp[0]);
            *reinterpret_cast<uint4*>(dst + 8) = *reinterpret_cast<const uint4*>(&tmp[8]);
        }
    };

    float rmax[4] = {-1e30f, -1e30f, -1e30f, -1e30f};

    const int frow  = lane & 15;
    const int fpack = lane >> 4;
    const unsigned short* aptr = &qs[(qh * 16 + frow) * LDSROW + fpack * 8];
    const unsigned short* bptr = &ds_[(kq * 16 + frow) * LDSROW + fpack * 8];

    auto mfma_max = [&](int t) {
        f32x4 acc = {0.f, 0.f, 0.f, 0.f};
        #pragma unroll
        for (int kc = 0; kc < 4; ++kc) {
            short8 a  = *reinterpret_cast<const short8*>(aptr + kc * 32);
            short8 bb = *reinterpret_cast<const short8*>(bptr + kc * 32);
            acc = __builtin_amdgcn_mfma_f32_16x16x32_bf16(a, bb, acc, 0, 0, 0);
        }
        const int col = t * KT + kq * 16 + frow;
        if (mks[col]) {
            #pragma unroll
            for (int r = 0; r < 4; ++r) rmax[r] = fmaxf(rmax[r], acc[r]);
        }
    };

    // ---- prologue: tile-0 loads in flight while queries normalize ----
    prefetch(va, 0);

    if (tid < 256) {   // waves 0-3: normalize the 32 query rows (8 threads/row)
        const int qrow = tid >> 3, qseg = tid & 7;
        const float* src = qreps + ((size_t)b * LQ + qrow) * DD + qseg * 16;
        float v[16];
        float ss = 0.f;
        #pragma unroll
        for (int i = 0; i < 16; i += 4) {
            float4 f = *reinterpret_cast<const float4*>(src + i);
            v[i] = f.x; v[i+1] = f.y; v[i+2] = f.z; v[i+3] = f.w;
            ss += f.x*f.x + f.y*f.y + f.z*f.z + f.w*f.w;
        }
        ss += __shfl_xor(ss, 1); ss += __shfl_xor(ss, 2); ss += __shfl_xor(ss, 4);
        const float rn = rsqrtf(fmaxf(ss, 1e-24f));
        unsigned short tmp[16];
        #pragma unroll
        for (int i = 0; i < 16; ++i) tmp[i] = f2bf(v[i] * rn);
        unsigned short* dst = &qs[qrow * LDSROW + qseg * 16];
        *reinterpret_cast<uint4*>(dst)     = *reinterpret_cast<const uint4*>(&tmp[0]);
        *reinterpret_cast<uint4*>(dst + 8) = *reinterpret_cast<const uint4*>(&tmp[8]);
    }

    // ---- main loop, register-double-buffered ----
    for (int t = 0; t < NT; t += 2) {
        if (t + 1 < NT) prefetch(vb, t + 1);
        stagewrite(va, t);
        __syncthreads();               // ds_ (and qs on first iter) visible
        mfma_max(t);
        __syncthreads();               // all reads of ds_ done

        if (t + 2 < NT) prefetch(va, t + 2);
        stagewrite(vb, t + 1);
        __syncthreads();
        mfma_max(t + 1);
        __syncthreads();
    }

    // ---- reduce max across the 16 k-columns within each wave ----
    #pragma unroll
    for (int r = 0; r < 4; ++r) {
        float m = rmax[r];
        m = fmaxf(m, __shfl_xor(m, 1));
        m = fmaxf(m, __shfl_xor(m, 2));
        m = fmaxf(m, __shfl_xor(m, 4));
        m = fmaxf(m, __shfl_xor(m, 8));
        rmax[r] = m;
    }
    if ((lane & 15) == 0) {
        const int qrow = qh * 16 + (lane >> 4) * 4;
        #pragma unroll
        for (int r = 0; r < 4; ++r) qmax[kq][qrow + r] = rmax[r];
    }
    __syncthreads();

    // ---- combine k-quarters, sum over 32 q rows ----
    if (w == 0) {
        float s = 0.f;
        if (lane < 32) {
            s = fmaxf(fmaxf(qmax[0][lane], qmax[1][lane]),
                      fmaxf(qmax[2][lane], qmax[3][lane]));
        }
        s += __shfl_xor(s, 1);  s += __shfl_xor(s, 2);  s += __shfl_xor(s, 4);
        s += __shfl_xor(s, 8);  s += __shfl_xor(s, 16); s += __shfl_xor(s, 32);
        if (lane == 0) scores[bn] = s;
    }
}

// One wave: thread b handles batch row b.
__global__ __launch_bounds__(64) void colbert_loss_kernel(
    const float* __restrict__ scores,   // [B*NWAY]
    const float* __restrict__ labels,   // [B][2*NWAY]
    float*       __restrict__ out)
{
    const int b = threadIdx.x;
    float sc[NWAY];
    float m = -1e30f;
    #pragma unroll
    for (int j = 0; j < NWAY; ++j) { sc[j] = scores[b * NWAY + j]; m = fmaxf(m, sc[j]); }
    float se = 0.f;
    #pragma unroll
    for (int j = 0; j < NWAY; ++j) se += expf(sc[j] - m);
    const float lse = m + logf(se);

    float lossb = 0.f, posb = 0.f;
    #pragma unroll
    for (int j = 0; j < NWAY; ++j) {
        const float ls = sc[j] - lse;
        const float tg = labels[b * 2 * NWAY + j];
        const float wv = labels[b * 2 * NWAY + NWAY + j];
        lossb += expf(tg) * (tg - ls);
        posb  += ls * wv;
    }
    float a = lossb, p = posb;
    #pragma unroll
    for (int d = 1; d < 64; d <<= 1) { a += __shfl_xor(a, d); p += __shfl_xor(p, d); }
    if (b == 0) out[0] = a / 512.0f - 0.1f * p;
}

extern "C" void kernel_launch(void* const* d_in, const int* in_sizes, int n_in,
                              void* d_out, int out_size, void* d_ws, size_t ws_size,
                              hipStream_t stream) {
    const float* qreps  = (const float*)d_in[0];
    const float* dreps  = (const float*)d_in[1];
    const int*   masks  = (const int*)d_in[2];
    const float* labels = (const float*)d_in[3];
    float* scores = (float*)d_ws;            // 512 floats
    float* out    = (float*)d_out;

    colbert_scores_kernel<<<NB * NWAY, 512, 0, stream>>>(qreps, dreps, masks, scores);
    colbert_loss_kernel<<<1, 64, 0, stream>>>(scores, labels, out);
}